// Round 11
// baseline (5258.378 us; speedup 1.0000x reference)
//
#include <hip/hip_runtime.h>
#include <hip/hip_fp16.h>
#include <math.h>

#define D 512
#define H 8
#define DH 64
#define NLAYERS 8
#define DFF 8
#define NC 10
#define KITERS 10
#define SEQ 1026
#define SEQP 1032
#define BATCH 16
#define MR (BATCH*SEQ)            // 16416 rows
#define NBUF ((size_t)MR * D)     // floats per big activation buffer
#define DD ((size_t)D * D)
#define NBH (BATCH*H)             // 128
#define NCHUNK 5                  // 5*256 = 1280 >= 1026 positions

typedef _Float16 f16;
typedef f16 f16x8 __attribute__((ext_vector_type(8)));
typedef float f32x4 __attribute__((ext_vector_type(4)));

__device__ __forceinline__ void split2(float x, float y, unsigned& uh, unsigned& ul) {
    __half hx = __float2half_rn(x), hy = __float2half_rn(y);
    __half lx = __float2half_rn(x - __half2float(hx));
    __half ly = __float2half_rn(y - __half2float(hy));
    uh = (unsigned)__half_as_ushort(hx) | ((unsigned)__half_as_ushort(hy) << 16);
    ul = (unsigned)__half_as_ushort(lx) | ((unsigned)__half_as_ushort(ly) << 16);
}

__device__ __forceinline__ float pe_val(int s, int d) {
    float e = (float)(d & ~1);
    float dv = expf(e * (-9.210340371976184f / 512.0f));   // ln(10000)/512
    float ph = (float)s * dv;
    return (d & 1) ? cosf(ph) : sinf(ph);
}

// ---------------- weight split+transpose (Wq,Wk,Wv): W[k][n] -> [l][3][n][k] f16 hi/lo ----------------
__launch_bounds__(256)
__global__ void convert_w(const float* __restrict__ Wq, const float* __restrict__ Wk,
                          const float* __restrict__ Wv,
                          ushort* __restrict__ whiT, ushort* __restrict__ wloT)
{
    __shared__ float tile[64][65];
    const int tid = threadIdx.x;
    const int k0 = blockIdx.x * 64, n0 = blockIdx.y * 64, m = blockIdx.z;
    const int which = m % 3, lyr = m / 3;
    const float* base;
    switch (which) { case 0: base = Wq; break; case 1: base = Wk; break;
                     default: base = Wv; }
    const float* W = base + (size_t)lyr * DD;
    {
        int r = tid >> 4, c = (tid & 15) * 4;
        #pragma unroll
        for (int p = 0; p < 4; ++p) {
            float4 v = *(const float4*)&W[(size_t)(k0 + r + p*16)*D + n0 + c];
            tile[r + p*16][c]   = v.x; tile[r + p*16][c+1] = v.y;
            tile[r + p*16][c+2] = v.z; tile[r + p*16][c+3] = v.w;
        }
    }
    __syncthreads();
    ushort* ohp = whiT + (size_t)m * DD;
    ushort* olp = wloT + (size_t)m * DD;
    {
        int nl = tid >> 3, kc = (tid & 7) * 8;
        #pragma unroll
        for (int p = 0; p < 2; ++p) {
            int n = nl + p*32;
            uint4 UH, UL;
            split2(tile[kc+0][n], tile[kc+1][n], UH.x, UL.x);
            split2(tile[kc+2][n], tile[kc+3][n], UH.y, UL.y);
            split2(tile[kc+4][n], tile[kc+5][n], UH.z, UL.z);
            split2(tile[kc+6][n], tile[kc+7][n], UH.w, UL.w);
            size_t off = (size_t)(n0 + n)*D + k0 + kc;
            *(uint4*)&ohp[off] = UH;
            *(uint4*)&olp[off] = UL;
        }
    }
}

// ---------------- embed ----------------
__launch_bounds__(256)
__global__ void embed_kernel(const float* __restrict__ x, const int* __restrict__ y,
    const float* __restrict__ muQ, const float* __restrict__ sigQ,
    const float* __restrict__ mu_w, const float* __restrict__ mu_b,
    const float* __restrict__ sig_w, const float* __restrict__ sig_b,
    const float* __restrict__ skel_w, const float* __restrict__ skel_b,
    float* __restrict__ z)
{
    __shared__ float xin[3072];
    const int bx = blockIdx.x, b = blockIdx.y, tid = threadIdx.x;
    if (bx < 2) {
        const float* Q  = (bx == 0) ? muQ  : sigQ;
        const float* W  = (bx == 0) ? mu_w : sig_w;
        const float* bb = (bx == 0) ? mu_b : sig_b;
        for (int i = tid; i < 3072; i += 256) {
            int a = y[b*6 + (i >> 9)];
            xin[i] = Q[a*D + (i & 511)];
        }
        __syncthreads();
        const int d0 = tid, d1 = tid + 256;
        float acc0 = bb[d0], acc1 = bb[d1];
        const float4* x4 = (const float4*)xin;
        for (int i4 = 0; i4 < 768; ++i4) {
            float4 xv = x4[i4];
            int r = i4 * 4;
            acc0 += xv.x*W[(size_t)(r+0)*D+d0] + xv.y*W[(size_t)(r+1)*D+d0]
                  + xv.z*W[(size_t)(r+2)*D+d0] + xv.w*W[(size_t)(r+3)*D+d0];
            acc1 += xv.x*W[(size_t)(r+0)*D+d1] + xv.y*W[(size_t)(r+1)*D+d1]
                  + xv.z*W[(size_t)(r+2)*D+d1] + xv.w*W[(size_t)(r+3)*D+d1];
        }
        size_t base = ((size_t)b*SEQ + bx) * D;
        z[base + d0] = acc0 + pe_val(bx, d0);
        z[base + d1] = acc1 + pe_val(bx, d1);
    } else {
        const int f0 = (bx - 2) * 4;
        for (int idx = tid; idx < 600; idx += 256) {
            int i = idx >> 2, ff = idx & 3;
            xin[idx] = x[((size_t)(b*150 + i))*1024 + f0 + ff];
        }
        __syncthreads();
        const float4* x4 = (const float4*)xin;
        for (int dd = 0; dd < 2; ++dd) {
            const int d = tid + dd*256;
            float a0, a1, a2, a3;
            a0 = a1 = a2 = a3 = skel_b[d];
            for (int i = 0; i < 150; ++i) {
                float4 xv = x4[i];
                float w = skel_w[(size_t)i*D + d];
                a0 += xv.x*w; a1 += xv.y*w; a2 += xv.z*w; a3 += xv.w*w;
            }
            float a[4] = {a0, a1, a2, a3};
            #pragma unroll
            for (int ff = 0; ff < 4; ++ff) {
                int s = f0 + ff + 2;
                z[((size_t)b*SEQ + s)*D + d] = a[ff] + pe_val(s, d);
            }
        }
    }
}

// ---------------- fused QKV split-f16 MFMA GEMM ----------------
__launch_bounds__(256)
__global__ void gemm_qkv(const float* __restrict__ A,
                         const ushort* __restrict__ Bhi_b, const ushort* __restrict__ Blo_b,
                         const float* __restrict__ bq, const float* __restrict__ bk,
                         const float* __restrict__ bv,
                         float* __restrict__ outbase, int M)
{
    __shared__ ushort Ah[128*40], Al[128*40], Bh[128*40], Bl[128*40];
    const int tid = threadIdx.x;
    const int m0 = blockIdx.y * 128, n0 = blockIdx.x * 128;
    const int zz = blockIdx.z;
    const ushort* Bhi = Bhi_b + (size_t)zz * DD;
    const ushort* Blo = Blo_b + (size_t)zz * DD;
    const float* bias = (zz == 0) ? bq : (zz == 1) ? bk : bv;
    float* out = outbase + (size_t)zz * NBUF;
    const int l = tid & 63, wv = tid >> 6;
    const int wr = wv >> 1, wc = wv & 1;

    f32x4 acc[4][4];
    #pragma unroll
    for (int mi = 0; mi < 4; ++mi)
        #pragma unroll
        for (int ni = 0; ni < 4; ++ni) acc[mi][ni] = (f32x4){0.f, 0.f, 0.f, 0.f};

    const int ar_s = tid >> 1, ac_s = (tid & 1) * 16;
    const bool va = (m0 + ar_s) < M;
    const int r0 = (tid*2) >> 2,   kc0 = ((tid*2) & 3) * 8;
    const int r1 = (tid*2+1) >> 2, kc1 = ((tid*2+1) & 3) * 8;
    const float4 fz = make_float4(0.f, 0.f, 0.f, 0.f);

    for (int kt = 0; kt < 16; ++kt) {
        const int kb = kt * 32;
        float4 a0 = fz, a1 = fz, a2 = fz, a3 = fz;
        if (va) {
            const float4* ap = (const float4*)&A[(size_t)(m0 + ar_s)*D + kb + ac_s];
            a0 = ap[0]; a1 = ap[1]; a2 = ap[2]; a3 = ap[3];
        }
        uint4 bh0 = *(const uint4*)&Bhi[(size_t)(n0+r0)*D + kb + kc0];
        uint4 bh1 = *(const uint4*)&Bhi[(size_t)(n0+r1)*D + kb + kc1];
        uint4 bl0 = *(const uint4*)&Blo[(size_t)(n0+r0)*D + kb + kc0];
        uint4 bl1 = *(const uint4*)&Blo[(size_t)(n0+r1)*D + kb + kc1];

        uint4 AH0, AL0, AH1, AL1;
        split2(a0.x, a0.y, AH0.x, AL0.x); split2(a0.z, a0.w, AH0.y, AL0.y);
        split2(a1.x, a1.y, AH0.z, AL0.z); split2(a1.z, a1.w, AH0.w, AL0.w);
        split2(a2.x, a2.y, AH1.x, AL1.x); split2(a2.z, a2.w, AH1.y, AL1.y);
        split2(a3.x, a3.y, AH1.z, AL1.z); split2(a3.z, a3.w, AH1.w, AL1.w);

        if (kt) __syncthreads();
        *(uint4*)&Ah[ar_s*40 + ac_s]     = AH0;
        *(uint4*)&Ah[ar_s*40 + ac_s + 8] = AH1;
        *(uint4*)&Al[ar_s*40 + ac_s]     = AL0;
        *(uint4*)&Al[ar_s*40 + ac_s + 8] = AL1;
        *(uint4*)&Bh[r0*40 + kc0] = bh0;  *(uint4*)&Bh[r1*40 + kc1] = bh1;
        *(uint4*)&Bl[r0*40 + kc0] = bl0;  *(uint4*)&Bl[r1*40 + kc1] = bl1;
        __syncthreads();

        const int ko = (l >> 4) * 8;
        f16x8 bhf[4], blf[4];
        #pragma unroll
        for (int ni = 0; ni < 4; ++ni) {
            int br = wc*64 + ni*16 + (l & 15);
            bhf[ni] = *(const f16x8*)&Bh[br*40 + ko];
            blf[ni] = *(const f16x8*)&Bl[br*40 + ko];
        }
        #pragma unroll
        for (int mi = 0; mi < 4; ++mi) {
            int ar = wr*64 + mi*16 + (l & 15);
            f16x8 ahf = *(const f16x8*)&Ah[ar*40 + ko];
            f16x8 alf = *(const f16x8*)&Al[ar*40 + ko];
            #pragma unroll
            for (int ni = 0; ni < 4; ++ni) {
                acc[mi][ni] = __builtin_amdgcn_mfma_f32_16x16x32_f16(ahf, bhf[ni], acc[mi][ni], 0, 0, 0);
                acc[mi][ni] = __builtin_amdgcn_mfma_f32_16x16x32_f16(ahf, blf[ni], acc[mi][ni], 0, 0, 0);
                acc[mi][ni] = __builtin_amdgcn_mfma_f32_16x16x32_f16(alf, bhf[ni], acc[mi][ni], 0, 0, 0);
            }
        }
    }

    const int col_base = n0 + wc*64 + (l & 15);
    const int row_base = m0 + wr*64 + ((l >> 4) << 2);
    #pragma unroll
    for (int ni = 0; ni < 4; ++ni) {
        const int col = col_base + ni*16;
        const float bv2 = bias[col];
        #pragma unroll
        for (int mi = 0; mi < 4; ++mi) {
            #pragma unroll
            for (int e = 0; e < 4; ++e) {
                const int row = row_base + mi*16 + e;
                if (row >= M) continue;
                float val = acc[mi][ni][e] + bv2;
                int bb = row / SEQ;
                int ss = row - bb*SEQ;
                int hh = col >> 6, dh = col & 63;
                out[((size_t)(bb*H + hh)*SEQ + ss)*DH + dh] = val;
            }
        }
    }
}

// ---------------- kmeans assignment: grid (NCHUNK, NBH), 1 position/thread ----------------
// INIT: centroids = q[:10]. Else: finalize from per-chunk partials (fixed order -> deterministic).
template<bool INIT>
__launch_bounds__(256)
__global__ void kassign(const float* __restrict__ q,
                        const float* __restrict__ partials, const float* __restrict__ pcnt,
                        unsigned char* __restrict__ assignbuf)
{
    __shared__ float cent[NC][DH];
    __shared__ float cnorm[NC];
    __shared__ float cntS[NC];
    const int tid = threadIdx.x;
    const int chunk = blockIdx.x, head = blockIdx.y;
    const float* qh = q + (size_t)head * SEQ * DH;

    if (INIT) {
        for (int i = tid; i < NC*DH; i += 256) ((float*)cent)[i] = qh[i];
    } else {
        if (tid < NC) {
            float s = 0.f;
            #pragma unroll
            for (int j = 0; j < NCHUNK; ++j) s += pcnt[((size_t)head*NCHUNK + j)*NC + tid];
            cntS[tid] = fmaxf(s, 1.f);
        }
        __syncthreads();
        for (int i = tid; i < NC*DH; i += 256) {
            int c = i >> 6;
            float s = 0.f;
            #pragma unroll
            for (int j = 0; j < NCHUNK; ++j) s += partials[((size_t)head*NCHUNK + j)*(NC*DH) + i];
            ((float*)cent)[i] = s / cntS[c];
        }
    }
    __syncthreads();
    if (tid < NC) {
        float sn = 0.f;
        #pragma unroll
        for (int i = 0; i < 16; ++i) {
            float4 cv = *(const float4*)&cent[tid][i*4];
            sn += cv.x*cv.x + cv.y*cv.y + cv.z*cv.z + cv.w*cv.w;
        }
        cnorm[tid] = sn;
    }
    __syncthreads();

    const int s = chunk*256 + tid;
    if (s < SEQ) {
        const float4* qrow4 = (const float4*)(qh + (size_t)s * DH);
        float acc[NC];
        #pragma unroll
        for (int c = 0; c < NC; ++c) acc[c] = 0.f;
        #pragma unroll 8
        for (int kq = 0; kq < 16; ++kq) {
            float4 qv = qrow4[kq];
            #pragma unroll
            for (int c = 0; c < NC; ++c) {
                float4 cv = *(const float4*)&cent[c][kq*4];
                acc[c] += qv.x*cv.x + qv.y*cv.y + qv.z*cv.z + qv.w*cv.w;
            }
        }
        int best = 0; float bd = 1e30f;
        #pragma unroll
        for (int c = 0; c < NC; ++c) {
            float dd = cnorm[c] - 2.f*acc[c];
            if (dd < bd) { bd = dd; best = c; }
        }
        assignbuf[(size_t)head*SEQP + s] = (unsigned char)best;
    }
}

// ---------------- kmeans update partials: grid (NCHUNK, NBH) ----------------
// wave w covers positions [chunk*256 + w*64, +64), lane = dim. No atomics; fixed-order reduce.
__launch_bounds__(256)
__global__ void kupdate(const float* __restrict__ q,
                        const unsigned char* __restrict__ assignbuf,
                        float* __restrict__ partials, float* __restrict__ pcnt)
{
    __shared__ float part[4][NC][DH];   // 40 KB
    __shared__ float pcw[4][NC];
    const int tid = threadIdx.x;
    const int wv = tid >> 6, lane = tid & 63;
    const int chunk = blockIdx.x, head = blockIdx.y;
    const float* qh = q + (size_t)head * SEQ * DH;
    const unsigned char* ah = assignbuf + (size_t)head * SEQP;

    float accq[NC], cw[NC];
    #pragma unroll
    for (int c = 0; c < NC; ++c) { accq[c] = 0.f; cw[c] = 0.f; }
    const int s0 = chunk*256 + wv*64;
    #pragma unroll 8
    for (int i = 0; i < 64; ++i) {
        int s = s0 + i;
        if (s < SEQ) {
            float qv = qh[(size_t)s*DH + lane];
            int c = ah[s];
            #pragma unroll
            for (int cc = 0; cc < NC; ++cc) {
                accq[cc] += (cc == c) ? qv : 0.f;
                cw[cc]   += (cc == c) ? 1.f : 0.f;
            }
        }
    }
    #pragma unroll
    for (int c = 0; c < NC; ++c) part[wv][c][lane] = accq[c];
    if (lane == 0) {
        #pragma unroll
        for (int c = 0; c < NC; ++c) pcw[wv][c] = cw[c];
    }
    __syncthreads();
    float* pp = partials + ((size_t)head*NCHUNK + chunk)*(NC*DH);
    for (int i = tid; i < NC*DH; i += 256) {
        const float* pf = &part[0][0][0];
        pp[i] = pf[i] + pf[640 + i] + pf[1280 + i] + pf[1920 + i];
    }
    if (tid < NC)
        pcnt[((size_t)head*NCHUNK + chunk)*NC + tid] = pcw[0][tid] + pcw[1][tid] + pcw[2][tid] + pcw[3][tid];
}

// ---------------- attention final: logits + softmax + A@v -> cent_out ----------------
__launch_bounds__(1024, 4)
__global__ void attn_final(const float* __restrict__ kk, const float* __restrict__ v,
                           const float* __restrict__ partials, const float* __restrict__ pcnt,
                           float* __restrict__ centout)
{
    __shared__ float At[NC][SEQP];       // 41.3 KB; doubles as part[16][NC][DH]
    __shared__ float cent[NC][DH];
    __shared__ float tailrow[2][DH];
    __shared__ float cntS[NC];
    __shared__ float redA[16][NC];
    __shared__ float redB[16][NC];
    __shared__ float Mc[NC];
    __shared__ float Sinv[NC];

    const int tid = threadIdx.x;
    const int wv = tid >> 6, lane = tid & 63;
    const int bh = blockIdx.x;
    const float* kh = kk + (size_t)bh * SEQ * DH;
    const float* vh = v  + (size_t)bh * SEQ * DH;
    float* part = &At[0][0];

    if (tid < NC) {
        float s = 0.f;
        #pragma unroll
        for (int j = 0; j < NCHUNK; ++j) s += pcnt[((size_t)bh*NCHUNK + j)*NC + tid];
        cntS[tid] = fmaxf(s, 1.f);
    }
    __syncthreads();
    if (tid < NC*DH) {
        int c = tid >> 6;
        float s = 0.f;
        #pragma unroll
        for (int j = 0; j < NCHUNK; ++j) s += partials[((size_t)bh*NCHUNK + j)*(NC*DH) + tid];
        ((float*)cent)[tid] = s / cntS[c];
    }
    if (tid >= NC*DH && tid < NC*DH + 2*DH) ((float*)tailrow)[tid - NC*DH] = kh[1024*DH + (tid - NC*DH)];
    __syncthreads();

    float lg[NC], lgt[NC];
    {
        const float4* krow4 = (const float4*)(kh + (size_t)tid * DH);
        #pragma unroll
        for (int c = 0; c < NC; ++c) lg[c] = 0.f;
        #pragma unroll 8
        for (int kq = 0; kq < 16; ++kq) {
            float4 kv = krow4[kq];
            #pragma unroll
            for (int c = 0; c < NC; ++c) {
                float4 cv = *(const float4*)&cent[c][kq*4];
                lg[c] += kv.x*cv.x + kv.y*cv.y + kv.z*cv.z + kv.w*cv.w;
            }
        }
        #pragma unroll
        for (int c = 0; c < NC; ++c) lg[c] *= 0.125f;
    }
    if (tid < 2) {
        #pragma unroll
        for (int c = 0; c < NC; ++c) {
            float acc = 0.f;
            #pragma unroll
            for (int i = 0; i < 64; ++i) acc += tailrow[tid][i]*cent[c][i];
            lgt[c] = 0.125f * acc;
        }
    }

    #pragma unroll
    for (int c = 0; c < NC; ++c) {
        float m = lg[c];
        if (tid < 2) m = fmaxf(m, lgt[c]);
        #pragma unroll
        for (int off = 32; off; off >>= 1) m = fmaxf(m, __shfl_xor(m, off, 64));
        if (lane == 0) redA[wv][c] = m;
    }
    __syncthreads();
    if (tid < NC) {
        float m = redA[0][tid];
        #pragma unroll
        for (int w = 1; w < 16; ++w) m = fmaxf(m, redA[w][tid]);
        Mc[tid] = m;
    }
    __syncthreads();
    #pragma unroll
    for (int c = 0; c < NC; ++c) lg[c] = expf(lg[c] - Mc[c]);
    if (tid < 2) {
        #pragma unroll
        for (int c = 0; c < NC; ++c) lgt[c] = expf(lgt[c] - Mc[c]);
    }
    #pragma unroll
    for (int c = 0; c < NC; ++c) {
        float s = lg[c] + ((tid < 2) ? lgt[c] : 0.f);
        #pragma unroll
        for (int off = 32; off; off >>= 1) s += __shfl_xor(s, off, 64);
        if (lane == 0) redB[wv][c] = s;
    }
    __syncthreads();
    if (tid < NC) {
        float s = 0.f;
        #pragma unroll
        for (int w = 0; w < 16; ++w) s += redB[w][tid];
        Sinv[tid] = 1.f / s;
    }
    __syncthreads();
    #pragma unroll
    for (int c = 0; c < NC; ++c) At[c][tid] = lg[c] * Sinv[c];
    if (tid < 2) {
        #pragma unroll
        for (int c = 0; c < NC; ++c) At[c][1024 + tid] = lgt[c] * Sinv[c];
    }
    __syncthreads();

    {
        float accv[NC];
        #pragma unroll
        for (int c = 0; c < NC; ++c) accv[c] = 0.f;
        const int s0 = wv * 64;
        for (int i = 0; i < 64; i += 4) {
            float vv0 = vh[(size_t)(s0+i  )*DH + lane];
            float vv1 = vh[(size_t)(s0+i+1)*DH + lane];
            float vv2 = vh[(size_t)(s0+i+2)*DH + lane];
            float vv3 = vh[(size_t)(s0+i+3)*DH + lane];
            #pragma unroll
            for (int c = 0; c < NC; ++c) {
                float4 av = *(const float4*)&At[c][s0+i];
                accv[c] += av.x*vv0 + av.y*vv1 + av.z*vv2 + av.w*vv3;
            }
        }
        if (wv < 2) {
            int s = 1024 + wv;
            float vv = vh[(size_t)s*DH + lane];
            #pragma unroll
            for (int c = 0; c < NC; ++c) accv[c] += At[c][s] * vv;
        }
        __syncthreads();
        #pragma unroll
        for (int c = 0; c < NC; ++c) part[(wv*NC + c)*DH + lane] = accv[c];
    }
    __syncthreads();
    if (tid < NC*DH) {
        float s = 0.f;
        #pragma unroll
        for (int w = 0; w < 16; ++w) s += part[w*(NC*DH) + tid];
        centout[(size_t)bh*(NC*DH) + tid] = s;
    }
}

// ---------------- P projection: P[bh][c][n] = cent_out[bh][c] @ Wo_h (fp32 exact) ----------------
__launch_bounds__(256)
__global__ void pproj_kernel(const float* __restrict__ centout, const float* __restrict__ Wo,
                             float* __restrict__ P)
{
    __shared__ float cs[NC][DH];
    const int tid = threadIdx.x;
    const int bh = blockIdx.x, h = bh & 7;
    const int n = blockIdx.y * 256 + tid;
    for (int i = tid; i < NC*DH; i += 256) ((float*)cs)[i] = centout[(size_t)bh*(NC*DH) + i];
    __syncthreads();
    float acc[NC];
    #pragma unroll
    for (int c = 0; c < NC; ++c) acc[c] = 0.f;
    #pragma unroll 8
    for (int d = 0; d < DH; ++d) {
        float wv = Wo[(size_t)(h*DH + d)*D + n];
        #pragma unroll
        for (int c = 0; c < NC; ++c) acc[c] += cs[c][d] * wv;
    }
    #pragma unroll
    for (int c = 0; c < NC; ++c)
        P[((size_t)bh*NC + c)*D + n] = acc[c];
}

// ---------------- fused o-gather + residual + LN1 + FFN + residual + LN2 ----------------
__launch_bounds__(256)
__global__ void ffn_ln_kernel(float* __restrict__ z,
    const float* __restrict__ P, const unsigned char* __restrict__ assignbuf,
    const float* __restrict__ bo,
    const float* __restrict__ g1, const float* __restrict__ c1,
    const float* __restrict__ W1, const float* __restrict__ b1,
    const float* __restrict__ W2, const float* __restrict__ b2,
    const float* __restrict__ g2, const float* __restrict__ c2)
{
    __shared__ float red[8];
    __shared__ float redh[4][DFF];
    const int row = blockIdx.x, tid = threadIdx.x;
    const int lane = tid & 63, wid = tid >> 6;
    const int b = row / SEQ, s = row - b*SEQ;

    float x0 = z[(size_t)row*D + tid]       + bo[tid];
    float x1 = z[(size_t)row*D + tid + 256] + bo[tid + 256];
    #pragma unroll
    for (int h = 0; h < H; ++h) {
        int a = assignbuf[(size_t)(b*H + h)*SEQP + s];
        const float* Pr = P + ((size_t)(b*H + h)*NC + a)*D;
        x0 += Pr[tid];
        x1 += Pr[tid + 256];
    }

    float sm = x0 + x1, ss = x0*x0 + x1*x1;
    #pragma unroll
    for (int off = 32; off; off >>= 1) {
        sm += __shfl_xor(sm, off, 64);
        ss += __shfl_xor(ss, off, 64);
    }
    if (lane == 0) { red[wid] = sm; red[4 + wid] = ss; }
    __syncthreads();
    float tot  = red[0] + red[1] + red[2] + red[3];
    float tot2 = red[4] + red[5] + red[6] + red[7];
    float mean = tot * (1.f/512.f);
    float var  = tot2 * (1.f/512.f) - mean*mean;
    float rstd = rsqrtf(var + 1e-5f);
    float za = (x0 - mean)*rstd*g1[tid]       + c1[tid];
    float zb = (x1 - mean)*rstd*g1[tid + 256] + c1[tid + 256];

    float p[DFF];
    #pragma unroll
    for (int j = 0; j < DFF; ++j)
        p[j] = za * W1[(size_t)tid*DFF + j] + zb * W1[(size_t)(tid+256)*DFF + j];
    #pragma unroll
    for (int off = 32; off; off >>= 1)
        #pragma unroll
        for (int j = 0; j < DFF; ++j) p[j] += __shfl_xor(p[j], off, 64);
    if (lane == 0) {
        #pragma unroll
        for (int j = 0; j < DFF; ++j) redh[wid][j] = p[j];
    }
    __syncthreads();
    float hv[DFF];
    #pragma unroll
    for (int j = 0; j < DFF; ++j)
        hv[j] = fmaxf(redh[0][j] + redh[1][j] + redh[2][j] + redh[3][j] + b1[j], 0.f);
    float y0 = b2[tid], y1 = b2[tid + 256];
    #pragma unroll
    for (int j = 0; j < DFF; ++j) {
        y0 += hv[j] * W2[(size_t)j*D + tid];
        y1 += hv[j] * W2[(size_t)j*D + tid + 256];
    }
    float t0 = za + y0, t1 = zb + y1;
    float s2 = t0 + t1, ss2 = t0*t0 + t1*t1;
    #pragma unroll
    for (int off = 32; off; off >>= 1) {
        s2  += __shfl_xor(s2,  off, 64);
        ss2 += __shfl_xor(ss2, off, 64);
    }
    if (lane == 0) { red[wid] = s2; red[4 + wid] = ss2; }
    __syncthreads();
    float tt  = red[0] + red[1] + red[2] + red[3];
    float tt2 = red[4] + red[5] + red[6] + red[7];
    float m2 = tt * (1.f/512.f);
    float v2 = tt2 * (1.f/512.f) - m2*m2;
    float rstd2 = rsqrtf(v2 + 1e-5f);
    float* zo = z + (size_t)row * D;
    zo[tid]       = (t0 - m2)*rstd2*g2[tid]       + c2[tid];
    zo[tid + 256] = (t1 - m2)*rstd2*g2[tid + 256] + c2[tid + 256];
}

// ---------------- extract mu / logvar ----------------
__launch_bounds__(256)
__global__ void extract_kernel(const float* __restrict__ z, float* __restrict__ out) {
    int i = blockIdx.x * 256 + threadIdx.x;
    if (i >= 2*BATCH*D) return;
    int half = i >> 13;
    int j = i & 8191;
    int b = j >> 9, d = j & 511;
    out[i] = z[((size_t)b*SEQ + half)*D + d];
}

extern "C" void kernel_launch(void* const* d_in, const int* in_sizes, int n_in,
                              void* d_out, int out_size, void* d_ws, size_t ws_size,
                              hipStream_t stream)
{
    const float* x      = (const float*)d_in[0];
    const int*   y      = (const int*)  d_in[1];
    const float* muQ    = (const float*)d_in[3];
    const float* sigQ   = (const float*)d_in[4];
    const float* mu_w   = (const float*)d_in[5];
    const float* mu_b   = (const float*)d_in[6];
    const float* sig_w  = (const float*)d_in[7];
    const float* sig_b  = (const float*)d_in[8];
    const float* skel_w = (const float*)d_in[9];
    const float* skel_b = (const float*)d_in[10];
    const float* Wq     = (const float*)d_in[11];
    const float* bq     = (const float*)d_in[12];
    const float* Wk     = (const float*)d_in[13];
    const float* bk     = (const float*)d_in[14];
    const float* Wv     = (const float*)d_in[15];
    const float* bv     = (const float*)d_in[16];
    const float* Wo     = (const float*)d_in[17];
    const float* bo     = (const float*)d_in[18];
    const float* g1     = (const float*)d_in[19];
    const float* c1     = (const float*)d_in[20];
    const float* g2     = (const float*)d_in[21];
    const float* c2     = (const float*)d_in[22];
    const float* W1     = (const float*)d_in[23];
    const float* b1     = (const float*)d_in[24];
    const float* W2     = (const float*)d_in[25];
    const float* b2     = (const float*)d_in[26];

    float*  z    = (float*)d_ws;
    float*  qb   = z  + NBUF;     // q,k,v contiguous
    float*  kb   = qb + NBUF;
    float*  vb   = kb + NBUF;
    ushort* wThi = (ushort*)(vb + NBUF);       // [8][3][512][512] f16 hi
    ushort* wTlo = wThi + 24*DD;               // f16 lo
    float*  partials = (float*)(wTlo + 24*DD); // [128][5][10][64]
    float*  pcnt     = partials + (size_t)NBH*NCHUNK*NC*DH;  // [128][5][10]
    float*  centbuf  = pcnt + (size_t)NBH*NCHUNK*NC;         // [128][10][64]
    float*  P        = centbuf + (size_t)NBH*NC*DH;          // [128][10][512]
    unsigned char* assignbuf = (unsigned char*)(P + (size_t)NBH*NC*D);  // [128][1032]

    convert_w<<<dim3(8, 8, 24), 256, 0, stream>>>(Wq, Wk, Wv, wThi, wTlo);

    embed_kernel<<<dim3(258, BATCH), 256, 0, stream>>>(
        x, y, muQ, sigQ, mu_w, mu_b, sig_w, sig_b, skel_w, skel_b, z);

    for (int l = 0; l < NLAYERS; ++l) {
        gemm_qkv<<<dim3(4, 129, 3), 256, 0, stream>>>(
            z, wThi + (size_t)l*3*DD, wTlo + (size_t)l*3*DD,
            bq + l*D, bk + l*D, bv + l*D, qb, MR);
        kassign<true><<<dim3(NCHUNK, NBH), 256, 0, stream>>>(qb, partials, pcnt, assignbuf);
        for (int it = 0; it < KITERS; ++it) {
            kupdate<<<dim3(NCHUNK, NBH), 256, 0, stream>>>(qb, assignbuf, partials, pcnt);
            kassign<false><<<dim3(NCHUNK, NBH), 256, 0, stream>>>(qb, partials, pcnt, assignbuf);
        }
        attn_final<<<NBH, 1024, 0, stream>>>(kb, vb, partials, pcnt, centbuf);
        pproj_kernel<<<dim3(NBH, 2), 256, 0, stream>>>(centbuf, Wo + (size_t)l*DD, P);
        ffn_ln_kernel<<<MR, 256, 0, stream>>>(z, P, assignbuf, bo + l*D,
            g1 + (size_t)l*D, c1 + (size_t)l*D,
            W1 + (size_t)l*D*DFF, b1 + (size_t)l*DFF,
            W2 + (size_t)l*DFF*D, b2 + (size_t)l*D,
            g2 + (size_t)l*D, c2 + (size_t)l*D);
    }
    extract_kernel<<<64, 256, 0, stream>>>(z, (float*)d_out);

    (void)in_sizes; (void)n_in; (void)out_size; (void)ws_size;
}

// Round 12
// 5255.547 us; speedup vs baseline: 1.0005x; 1.0005x over previous
//
#include <hip/hip_runtime.h>
#include <hip/hip_fp16.h>
#include <math.h>

#define D 512
#define H 8
#define DH 64
#define NLAYERS 8
#define DFF 8
#define NC 10
#define KITERS 10
#define SEQ 1026
#define SEQP 1032
#define BATCH 16
#define MR (BATCH*SEQ)            // 16416 rows
#define NBUF ((size_t)MR * D)     // floats per big activation buffer
#define DD ((size_t)D * D)
#define NBH (BATCH*H)             // 128
#define QTSZ ((size_t)NBH * DH * SEQP)   // transposed q buffer

typedef _Float16 f16;
typedef f16 f16x8 __attribute__((ext_vector_type(8)));
typedef float f32x4 __attribute__((ext_vector_type(4)));

__device__ __forceinline__ void split2(float x, float y, unsigned& uh, unsigned& ul) {
    __half hx = __float2half_rn(x), hy = __float2half_rn(y);
    __half lx = __float2half_rn(x - __half2float(hx));
    __half ly = __float2half_rn(y - __half2float(hy));
    uh = (unsigned)__half_as_ushort(hx) | ((unsigned)__half_as_ushort(hy) << 16);
    ul = (unsigned)__half_as_ushort(lx) | ((unsigned)__half_as_ushort(ly) << 16);
}

__device__ __forceinline__ float pe_val(int s, int d) {
    float e = (float)(d & ~1);
    float dv = expf(e * (-9.210340371976184f / 512.0f));   // ln(10000)/512
    float ph = (float)s * dv;
    return (d & 1) ? cosf(ph) : sinf(ph);
}

// ---------------- weight split+transpose (Wq,Wk,Wv): W[k][n] -> [l][3][n][k] f16 hi/lo ----------------
__launch_bounds__(256)
__global__ void convert_w(const float* __restrict__ Wq, const float* __restrict__ Wk,
                          const float* __restrict__ Wv,
                          ushort* __restrict__ whiT, ushort* __restrict__ wloT)
{
    __shared__ float tile[64][65];
    const int tid = threadIdx.x;
    const int k0 = blockIdx.x * 64, n0 = blockIdx.y * 64, m = blockIdx.z;
    const int which = m % 3, lyr = m / 3;
    const float* base;
    switch (which) { case 0: base = Wq; break; case 1: base = Wk; break;
                     default: base = Wv; }
    const float* W = base + (size_t)lyr * DD;
    {
        int r = tid >> 4, c = (tid & 15) * 4;
        #pragma unroll
        for (int p = 0; p < 4; ++p) {
            float4 v = *(const float4*)&W[(size_t)(k0 + r + p*16)*D + n0 + c];
            tile[r + p*16][c]   = v.x; tile[r + p*16][c+1] = v.y;
            tile[r + p*16][c+2] = v.z; tile[r + p*16][c+3] = v.w;
        }
    }
    __syncthreads();
    ushort* ohp = whiT + (size_t)m * DD;
    ushort* olp = wloT + (size_t)m * DD;
    {
        int nl = tid >> 3, kc = (tid & 7) * 8;
        #pragma unroll
        for (int p = 0; p < 2; ++p) {
            int n = nl + p*32;
            uint4 UH, UL;
            split2(tile[kc+0][n], tile[kc+1][n], UH.x, UL.x);
            split2(tile[kc+2][n], tile[kc+3][n], UH.y, UL.y);
            split2(tile[kc+4][n], tile[kc+5][n], UH.z, UL.z);
            split2(tile[kc+6][n], tile[kc+7][n], UH.w, UL.w);
            size_t off = (size_t)(n0 + n)*D + k0 + kc;
            *(uint4*)&ohp[off] = UH;
            *(uint4*)&olp[off] = UL;
        }
    }
}

// ---------------- embed ----------------
__launch_bounds__(256)
__global__ void embed_kernel(const float* __restrict__ x, const int* __restrict__ y,
    const float* __restrict__ muQ, const float* __restrict__ sigQ,
    const float* __restrict__ mu_w, const float* __restrict__ mu_b,
    const float* __restrict__ sig_w, const float* __restrict__ sig_b,
    const float* __restrict__ skel_w, const float* __restrict__ skel_b,
    float* __restrict__ z)
{
    __shared__ float xin[3072];
    const int bx = blockIdx.x, b = blockIdx.y, tid = threadIdx.x;
    if (bx < 2) {
        const float* Q  = (bx == 0) ? muQ  : sigQ;
        const float* W  = (bx == 0) ? mu_w : sig_w;
        const float* bb = (bx == 0) ? mu_b : sig_b;
        for (int i = tid; i < 3072; i += 256) {
            int a = y[b*6 + (i >> 9)];
            xin[i] = Q[a*D + (i & 511)];
        }
        __syncthreads();
        const int d0 = tid, d1 = tid + 256;
        float acc0 = bb[d0], acc1 = bb[d1];
        const float4* x4 = (const float4*)xin;
        for (int i4 = 0; i4 < 768; ++i4) {
            float4 xv = x4[i4];
            int r = i4 * 4;
            acc0 += xv.x*W[(size_t)(r+0)*D+d0] + xv.y*W[(size_t)(r+1)*D+d0]
                  + xv.z*W[(size_t)(r+2)*D+d0] + xv.w*W[(size_t)(r+3)*D+d0];
            acc1 += xv.x*W[(size_t)(r+0)*D+d1] + xv.y*W[(size_t)(r+1)*D+d1]
                  + xv.z*W[(size_t)(r+2)*D+d1] + xv.w*W[(size_t)(r+3)*D+d1];
        }
        size_t base = ((size_t)b*SEQ + bx) * D;
        z[base + d0] = acc0 + pe_val(bx, d0);
        z[base + d1] = acc1 + pe_val(bx, d1);
    } else {
        const int f0 = (bx - 2) * 4;
        for (int idx = tid; idx < 600; idx += 256) {
            int i = idx >> 2, ff = idx & 3;
            xin[idx] = x[((size_t)(b*150 + i))*1024 + f0 + ff];
        }
        __syncthreads();
        const float4* x4 = (const float4*)xin;
        for (int dd = 0; dd < 2; ++dd) {
            const int d = tid + dd*256;
            float a0, a1, a2, a3;
            a0 = a1 = a2 = a3 = skel_b[d];
            for (int i = 0; i < 150; ++i) {
                float4 xv = x4[i];
                float w = skel_w[(size_t)i*D + d];
                a0 += xv.x*w; a1 += xv.y*w; a2 += xv.z*w; a3 += xv.w*w;
            }
            float a[4] = {a0, a1, a2, a3};
            #pragma unroll
            for (int ff = 0; ff < 4; ++ff) {
                int s = f0 + ff + 2;
                z[((size_t)b*SEQ + s)*D + d] = a[ff] + pe_val(s, d);
            }
        }
    }
}

// ---------------- fused QKV split-f16 MFMA GEMM ----------------
// blockIdx.z selects {q,k,v}. q is written TRANSPOSED: qT[bh][dh][SEQP] (for
// coalesced kmeans-assignment reads in attn); k,v row-major (bh, s, dh).
__launch_bounds__(256)
__global__ void gemm_qkv(const float* __restrict__ A,
                         const ushort* __restrict__ Bhi_b, const ushort* __restrict__ Blo_b,
                         const float* __restrict__ bq, const float* __restrict__ bk,
                         const float* __restrict__ bv,
                         float* __restrict__ qoutT, float* __restrict__ kout,
                         float* __restrict__ vout, int M)
{
    __shared__ ushort Ah[128*40], Al[128*40], Bh[128*40], Bl[128*40];
    const int tid = threadIdx.x;
    const int m0 = blockIdx.y * 128, n0 = blockIdx.x * 128;
    const int zz = blockIdx.z;
    const ushort* Bhi = Bhi_b + (size_t)zz * DD;
    const ushort* Blo = Blo_b + (size_t)zz * DD;
    const float* bias = (zz == 0) ? bq : (zz == 1) ? bk : bv;
    float* out = (zz == 0) ? qoutT : (zz == 1) ? kout : vout;
    const int l = tid & 63, wv = tid >> 6;
    const int wr = wv >> 1, wc = wv & 1;

    f32x4 acc[4][4];
    #pragma unroll
    for (int mi = 0; mi < 4; ++mi)
        #pragma unroll
        for (int ni = 0; ni < 4; ++ni) acc[mi][ni] = (f32x4){0.f, 0.f, 0.f, 0.f};

    const int ar_s = tid >> 1, ac_s = (tid & 1) * 16;
    const bool va = (m0 + ar_s) < M;
    const int r0 = (tid*2) >> 2,   kc0 = ((tid*2) & 3) * 8;
    const int r1 = (tid*2+1) >> 2, kc1 = ((tid*2+1) & 3) * 8;
    const float4 fz = make_float4(0.f, 0.f, 0.f, 0.f);

    for (int kt = 0; kt < 16; ++kt) {
        const int kb = kt * 32;
        float4 a0 = fz, a1 = fz, a2 = fz, a3 = fz;
        if (va) {
            const float4* ap = (const float4*)&A[(size_t)(m0 + ar_s)*D + kb + ac_s];
            a0 = ap[0]; a1 = ap[1]; a2 = ap[2]; a3 = ap[3];
        }
        uint4 bh0 = *(const uint4*)&Bhi[(size_t)(n0+r0)*D + kb + kc0];
        uint4 bh1 = *(const uint4*)&Bhi[(size_t)(n0+r1)*D + kb + kc1];
        uint4 bl0 = *(const uint4*)&Blo[(size_t)(n0+r0)*D + kb + kc0];
        uint4 bl1 = *(const uint4*)&Blo[(size_t)(n0+r1)*D + kb + kc1];

        uint4 AH0, AL0, AH1, AL1;
        split2(a0.x, a0.y, AH0.x, AL0.x); split2(a0.z, a0.w, AH0.y, AL0.y);
        split2(a1.x, a1.y, AH0.z, AL0.z); split2(a1.z, a1.w, AH0.w, AL0.w);
        split2(a2.x, a2.y, AH1.x, AL1.x); split2(a2.z, a2.w, AH1.y, AL1.y);
        split2(a3.x, a3.y, AH1.z, AL1.z); split2(a3.z, a3.w, AH1.w, AL1.w);

        if (kt) __syncthreads();
        *(uint4*)&Ah[ar_s*40 + ac_s]     = AH0;
        *(uint4*)&Ah[ar_s*40 + ac_s + 8] = AH1;
        *(uint4*)&Al[ar_s*40 + ac_s]     = AL0;
        *(uint4*)&Al[ar_s*40 + ac_s + 8] = AL1;
        *(uint4*)&Bh[r0*40 + kc0] = bh0;  *(uint4*)&Bh[r1*40 + kc1] = bh1;
        *(uint4*)&Bl[r0*40 + kc0] = bl0;  *(uint4*)&Bl[r1*40 + kc1] = bl1;
        __syncthreads();

        const int ko = (l >> 4) * 8;
        f16x8 bhf[4], blf[4];
        #pragma unroll
        for (int ni = 0; ni < 4; ++ni) {
            int br = wc*64 + ni*16 + (l & 15);
            bhf[ni] = *(const f16x8*)&Bh[br*40 + ko];
            blf[ni] = *(const f16x8*)&Bl[br*40 + ko];
        }
        #pragma unroll
        for (int mi = 0; mi < 4; ++mi) {
            int ar = wr*64 + mi*16 + (l & 15);
            f16x8 ahf = *(const f16x8*)&Ah[ar*40 + ko];
            f16x8 alf = *(const f16x8*)&Al[ar*40 + ko];
            #pragma unroll
            for (int ni = 0; ni < 4; ++ni) {
                acc[mi][ni] = __builtin_amdgcn_mfma_f32_16x16x32_f16(ahf, bhf[ni], acc[mi][ni], 0, 0, 0);
                acc[mi][ni] = __builtin_amdgcn_mfma_f32_16x16x32_f16(ahf, blf[ni], acc[mi][ni], 0, 0, 0);
                acc[mi][ni] = __builtin_amdgcn_mfma_f32_16x16x32_f16(alf, bhf[ni], acc[mi][ni], 0, 0, 0);
            }
        }
    }

    const int col_base = n0 + wc*64 + (l & 15);
    const int row_base = m0 + wr*64 + ((l >> 4) << 2);
    #pragma unroll
    for (int ni = 0; ni < 4; ++ni) {
        const int col = col_base + ni*16;
        const float bv2 = bias[col];
        const int hh = col >> 6, dh = col & 63;
        #pragma unroll
        for (int mi = 0; mi < 4; ++mi) {
            #pragma unroll
            for (int e = 0; e < 4; ++e) {
                const int row = row_base + mi*16 + e;
                if (row >= M) continue;
                float val = acc[mi][ni][e] + bv2;
                int bb = row / SEQ;
                int ss = row - bb*SEQ;
                if (zz == 0) {
                    out[((size_t)(bb*H + hh)*DH + dh)*SEQP + ss] = val;
                } else {
                    out[((size_t)(bb*H + hh)*SEQ + ss)*DH + dh] = val;
                }
            }
        }
    }
}

// ---------------- clustered attention: 1 block (1024 thr) per (b,h) ----------------
// q is TRANSPOSED qT[dh][SEQP]: assignment reads qT[d*SEQP + tid] (coalesced);
// update: wave owns 4 dims, lane scans positions (coalesced), 64-lane shuffle
// reduce writes centN[c][d] directly (no part buffer). Exports cent_out + assign.
__launch_bounds__(1024, 4)
__global__ void attn_kernel(const float* __restrict__ qT, const float* __restrict__ kk,
                            const float* __restrict__ v,
                            float* __restrict__ centout, unsigned char* __restrict__ assignout)
{
    __shared__ float At[NC][SEQP];       // 41.3 KB; doubles as part[16][NC][DH] for AV
    __shared__ float cent[NC][DH];
    __shared__ float centN[NC][DH];
    __shared__ float tailrow[2][DH];     // q tail rows; later k tail rows
    __shared__ float cnorm[NC];
    __shared__ int   cnt[NC];
    __shared__ int   chg;
    __shared__ unsigned char assign[1028];
    __shared__ float redA[16][NC];
    __shared__ float redB[16][NC];
    __shared__ float Mc[NC];
    __shared__ float Sinv[NC];

    const int tid = threadIdx.x;
    const int wv = tid >> 6, lane = tid & 63;
    const int bh = blockIdx.x;
    const float* qh = qT + (size_t)bh * DH * SEQP;   // [64][1032]
    const float* kh = kk + (size_t)bh * SEQ * DH;
    const float* vh = v  + (size_t)bh * SEQ * DH;
    float* part = &At[0][0];             // [16][NC][DH] flat (AV phase only)

    // init: cent[c][d] = q position c, dim d = qh[d*SEQP + c]; stage q tail rows
    if (tid < NC*DH) {
        int c = tid >> 6, d = tid & 63;
        cent[c][d] = qh[(size_t)d*SEQP + c];
    }
    if (tid >= NC*DH && tid < NC*DH + 2*DH) {
        int i = tid - NC*DH, t = i >> 6, d = i & 63;
        tailrow[t][d] = qh[(size_t)d*SEQP + 1024 + t];
    }
    __syncthreads();

    int prev_a = -1, prev_t = -1;
    for (int iter = 0; iter <= KITERS; ++iter) {
        if (tid < NC) {
            float sn = 0.f;
            #pragma unroll
            for (int i = 0; i < 16; ++i) {
                float4 cv = *(const float4*)&cent[tid][i*4];
                sn += cv.x*cv.x + cv.y*cv.y + cv.z*cv.z + cv.w*cv.w;
            }
            cnorm[tid] = sn;
            cnt[tid] = 0;
        }
        if (tid == 0) chg = 0;
        __syncthreads();

        // ---- assignment: position s=tid; coalesced transposed-q reads ----
        int a_reg;
        {
            float acc[NC];
            #pragma unroll
            for (int c = 0; c < NC; ++c) acc[c] = 0.f;
            #pragma unroll 4
            for (int d4 = 0; d4 < 16; ++d4) {
                float q0 = qh[(size_t)(d4*4+0)*SEQP + tid];
                float q1 = qh[(size_t)(d4*4+1)*SEQP + tid];
                float q2 = qh[(size_t)(d4*4+2)*SEQP + tid];
                float q3 = qh[(size_t)(d4*4+3)*SEQP + tid];
                #pragma unroll
                for (int c = 0; c < NC; ++c) {
                    float4 cv = *(const float4*)&cent[c][d4*4];
                    acc[c] += q0*cv.x + q1*cv.y + q2*cv.z + q3*cv.w;
                }
            }
            int best = 0; float bd = 1e30f;
            #pragma unroll
            for (int c = 0; c < NC; ++c) {
                float dd = cnorm[c] - 2.f*acc[c];
                if (dd < bd) { bd = dd; best = c; }
            }
            a_reg = best;
            assign[tid] = (unsigned char)best;
        }
        {
            unsigned long long mm = __ballot(a_reg != prev_a);
            if (lane == 0 && mm) atomicAdd(&chg, 1);
            prev_a = a_reg;
        }
        if (iter < KITERS) {
            #pragma unroll
            for (int c = 0; c < NC; ++c) {
                unsigned long long m = __ballot(a_reg == c);
                if (lane == 0 && m) atomicAdd(&cnt[c], __popcll(m));
            }
        }
        if (tid < 2) {          // tail positions 1024,1025 (from LDS tailrow)
            int best = 0; float bd = 1e30f;
            #pragma unroll
            for (int c = 0; c < NC; ++c) {
                float acc = 0.f;
                #pragma unroll
                for (int i = 0; i < 64; ++i) acc += tailrow[tid][i]*cent[c][i];
                float dd = cnorm[c] - 2.f*acc;
                if (dd < bd) { bd = dd; best = c; }
            }
            assign[1024 + tid] = (unsigned char)best;
            if (best != prev_t) atomicAdd(&chg, 1);
            prev_t = best;
            if (iter < KITERS) atomicAdd(&cnt[best], 1);
        }
        __syncthreads();
        if (iter == KITERS) break;
        if (chg == 0) break;    // bitwise-exact fixed point

        // ---- update: wave wv owns dims 4wv..4wv+3; lane scans positions ----
        {
            #pragma unroll
            for (int dd = 0; dd < 4; ++dd) {
                const int d = wv*4 + dd;
                float accq[NC];
                #pragma unroll
                for (int c = 0; c < NC; ++c) accq[c] = 0.f;
                #pragma unroll 4
                for (int i = 0; i < 16; ++i) {
                    int s = i*64 + lane;
                    float qv = qh[(size_t)d*SEQP + s];
                    int c = assign[s];
                    #pragma unroll
                    for (int cc = 0; cc < NC; ++cc) accq[cc] += (cc == c) ? qv : 0.f;
                }
                if (lane < 2) {
                    int c = assign[1024 + lane];
                    float qv = tailrow[lane][d];
                    #pragma unroll
                    for (int cc = 0; cc < NC; ++cc) accq[cc] += (cc == c) ? qv : 0.f;
                }
                #pragma unroll
                for (int c = 0; c < NC; ++c) {
                    float s = accq[c];
                    #pragma unroll
                    for (int off = 32; off; off >>= 1) s += __shfl_xor(s, off, 64);
                    if (lane == 0) centN[c][d] = s;
                }
            }
        }
        __syncthreads();
        if (tid < NC*DH) {
            int c = tid >> 6, d = tid & 63;
            cent[c][d] = centN[c][d] / fmaxf((float)cnt[c], 1.f);
        }
        __syncthreads();
    }

    // ---- logits: k row streamed from global; tailrow re-staged with k tails ----
    if (tid < 2*DH) ((float*)tailrow)[tid] = kh[1024*DH + tid];
    __syncthreads();

    float lg[NC], lgt[NC];
    {
        const float4* krow4 = (const float4*)(kh + (size_t)tid * DH);
        #pragma unroll
        for (int c = 0; c < NC; ++c) lg[c] = 0.f;
        #pragma unroll 8
        for (int kq = 0; kq < 16; ++kq) {
            float4 kv = krow4[kq];
            #pragma unroll
            for (int c = 0; c < NC; ++c) {
                float4 cv = *(const float4*)&cent[c][kq*4];
                lg[c] += kv.x*cv.x + kv.y*cv.y + kv.z*cv.z + kv.w*cv.w;
            }
        }
        #pragma unroll
        for (int c = 0; c < NC; ++c) lg[c] *= 0.125f;
    }
    if (tid < 2) {
        #pragma unroll
        for (int c = 0; c < NC; ++c) {
            float acc = 0.f;
            #pragma unroll
            for (int i = 0; i < 64; ++i) acc += tailrow[tid][i]*cent[c][i];
            lgt[c] = 0.125f * acc;
        }
    }

    #pragma unroll
    for (int c = 0; c < NC; ++c) {
        float m = lg[c];
        if (tid < 2) m = fmaxf(m, lgt[c]);
        #pragma unroll
        for (int off = 32; off; off >>= 1) m = fmaxf(m, __shfl_xor(m, off, 64));
        if (lane == 0) redA[wv][c] = m;
    }
    __syncthreads();
    if (tid < NC) {
        float m = redA[0][tid];
        #pragma unroll
        for (int w = 1; w < 16; ++w) m = fmaxf(m, redA[w][tid]);
        Mc[tid] = m;
    }
    __syncthreads();
    #pragma unroll
    for (int c = 0; c < NC; ++c) lg[c] = expf(lg[c] - Mc[c]);
    if (tid < 2) {
        #pragma unroll
        for (int c = 0; c < NC; ++c) lgt[c] = expf(lgt[c] - Mc[c]);
    }
    #pragma unroll
    for (int c = 0; c < NC; ++c) {
        float s = lg[c] + ((tid < 2) ? lgt[c] : 0.f);
        #pragma unroll
        for (int off = 32; off; off >>= 1) s += __shfl_xor(s, off, 64);
        if (lane == 0) redB[wv][c] = s;
    }
    __syncthreads();
    if (tid < NC) {
        float s = 0.f;
        #pragma unroll
        for (int w = 0; w < 16; ++w) s += redB[w][tid];
        Sinv[tid] = 1.f / s;
    }
    __syncthreads();
    #pragma unroll
    for (int c = 0; c < NC; ++c) At[c][tid] = lg[c] * Sinv[c];
    if (tid < 2) {
        #pragma unroll
        for (int c = 0; c < NC; ++c) At[c][1024 + tid] = lgt[c] * Sinv[c];
    }
    __syncthreads();

    // ---- A @ v -> cent_out; export ----
    {
        float accv[NC];
        #pragma unroll
        for (int c = 0; c < NC; ++c) accv[c] = 0.f;
        const int s0 = wv * 64;
        for (int i = 0; i < 64; i += 4) {
            float vv0 = vh[(size_t)(s0+i  )*DH + lane];
            float vv1 = vh[(size_t)(s0+i+1)*DH + lane];
            float vv2 = vh[(size_t)(s0+i+2)*DH + lane];
            float vv3 = vh[(size_t)(s0+i+3)*DH + lane];
            #pragma unroll
            for (int c = 0; c < NC; ++c) {
                float4 av = *(const float4*)&At[c][s0+i];
                accv[c] += av.x*vv0 + av.y*vv1 + av.z*vv2 + av.w*vv3;
            }
        }
        if (wv < 2) {
            int s = 1024 + wv;
            float vv = vh[(size_t)s*DH + lane];
            #pragma unroll
            for (int c = 0; c < NC; ++c) accv[c] += At[c][s] * vv;
        }
        __syncthreads();
        #pragma unroll
        for (int c = 0; c < NC; ++c) part[(wv*NC + c)*DH + lane] = accv[c];
    }
    __syncthreads();
    if (tid < NC*DH) {
        float s = 0.f;
        #pragma unroll
        for (int w = 0; w < 16; ++w) s += part[w*(NC*DH) + tid];
        centout[(size_t)bh*(NC*DH) + tid] = s;
    }
    for (int i = tid; i < SEQ; i += 1024)
        assignout[(size_t)bh*SEQP + i] = assign[i];
}

// ---------------- P projection: P[bh][c][n] = cent_out[bh][c] @ Wo_h (fp32 exact) ----------------
__launch_bounds__(256)
__global__ void pproj_kernel(const float* __restrict__ centout, const float* __restrict__ Wo,
                             float* __restrict__ P)
{
    __shared__ float cs[NC][DH];
    const int tid = threadIdx.x;
    const int bh = blockIdx.x, h = bh & 7;
    const int n = blockIdx.y * 256 + tid;
    for (int i = tid; i < NC*DH; i += 256) ((float*)cs)[i] = centout[(size_t)bh*(NC*DH) + i];
    __syncthreads();
    float acc[NC];
    #pragma unroll
    for (int c = 0; c < NC; ++c) acc[c] = 0.f;
    #pragma unroll 8
    for (int d = 0; d < DH; ++d) {
        float wv = Wo[(size_t)(h*DH + d)*D + n];
        #pragma unroll
        for (int c = 0; c < NC; ++c) acc[c] += cs[c][d] * wv;
    }
    #pragma unroll
    for (int c = 0; c < NC; ++c)
        P[((size_t)bh*NC + c)*D + n] = acc[c];
}

// ---------------- fused o-gather + residual + LN1 + FFN + residual + LN2 ----------------
__launch_bounds__(256)
__global__ void ffn_ln_kernel(float* __restrict__ z,
    const float* __restrict__ P, const unsigned char* __restrict__ assignbuf,
    const float* __restrict__ bo,
    const float* __restrict__ g1, const float* __restrict__ c1,
    const float* __restrict__ W1, const float* __restrict__ b1,
    const float* __restrict__ W2, const float* __restrict__ b2,
    const float* __restrict__ g2, const float* __restrict__ c2)
{
    __shared__ float red[8];
    __shared__ float redh[4][DFF];
    const int row = blockIdx.x, tid = threadIdx.x;
    const int lane = tid & 63, wid = tid >> 6;
    const int b = row / SEQ, s = row - b*SEQ;

    float x0 = z[(size_t)row*D + tid]       + bo[tid];
    float x1 = z[(size_t)row*D + tid + 256] + bo[tid + 256];
    #pragma unroll
    for (int h = 0; h < H; ++h) {
        int a = assignbuf[(size_t)(b*H + h)*SEQP + s];
        const float* Pr = P + ((size_t)(b*H + h)*NC + a)*D;
        x0 += Pr[tid];
        x1 += Pr[tid + 256];
    }

    float sm = x0 + x1, ss = x0*x0 + x1*x1;
    #pragma unroll
    for (int off = 32; off; off >>= 1) {
        sm += __shfl_xor(sm, off, 64);
        ss += __shfl_xor(ss, off, 64);
    }
    if (lane == 0) { red[wid] = sm; red[4 + wid] = ss; }
    __syncthreads();
    float tot  = red[0] + red[1] + red[2] + red[3];
    float tot2 = red[4] + red[5] + red[6] + red[7];
    float mean = tot * (1.f/512.f);
    float var  = tot2 * (1.f/512.f) - mean*mean;
    float rstd = rsqrtf(var + 1e-5f);
    float za = (x0 - mean)*rstd*g1[tid]       + c1[tid];
    float zb = (x1 - mean)*rstd*g1[tid + 256] + c1[tid + 256];

    float p[DFF];
    #pragma unroll
    for (int j = 0; j < DFF; ++j)
        p[j] = za * W1[(size_t)tid*DFF + j] + zb * W1[(size_t)(tid+256)*DFF + j];
    #pragma unroll
    for (int off = 32; off; off >>= 1)
        #pragma unroll
        for (int j = 0; j < DFF; ++j) p[j] += __shfl_xor(p[j], off, 64);
    if (lane == 0) {
        #pragma unroll
        for (int j = 0; j < DFF; ++j) redh[wid][j] = p[j];
    }
    __syncthreads();
    float hv[DFF];
    #pragma unroll
    for (int j = 0; j < DFF; ++j)
        hv[j] = fmaxf(redh[0][j] + redh[1][j] + redh[2][j] + redh[3][j] + b1[j], 0.f);
    float y0 = b2[tid], y1 = b2[tid + 256];
    #pragma unroll
    for (int j = 0; j < DFF; ++j) {
        y0 += hv[j] * W2[(size_t)j*D + tid];
        y1 += hv[j] * W2[(size_t)j*D + tid + 256];
    }
    float t0 = za + y0, t1 = zb + y1;
    float s2 = t0 + t1, ss2 = t0*t0 + t1*t1;
    #pragma unroll
    for (int off = 32; off; off >>= 1) {
        s2  += __shfl_xor(s2,  off, 64);
        ss2 += __shfl_xor(ss2, off, 64);
    }
    if (lane == 0) { red[wid] = s2; red[4 + wid] = ss2; }
    __syncthreads();
    float tt  = red[0] + red[1] + red[2] + red[3];
    float tt2 = red[4] + red[5] + red[6] + red[7];
    float m2 = tt * (1.f/512.f);
    float v2 = tt2 * (1.f/512.f) - m2*m2;
    float rstd2 = rsqrtf(v2 + 1e-5f);
    float* zo = z + (size_t)row * D;
    zo[tid]       = (t0 - m2)*rstd2*g2[tid]       + c2[tid];
    zo[tid + 256] = (t1 - m2)*rstd2*g2[tid + 256] + c2[tid + 256];
}

// ---------------- extract mu / logvar ----------------
__launch_bounds__(256)
__global__ void extract_kernel(const float* __restrict__ z, float* __restrict__ out) {
    int i = blockIdx.x * 256 + threadIdx.x;
    if (i >= 2*BATCH*D) return;
    int half = i >> 13;
    int j = i & 8191;
    int b = j >> 9, d = j & 511;
    out[i] = z[((size_t)b*SEQ + half)*D + d];
}

extern "C" void kernel_launch(void* const* d_in, const int* in_sizes, int n_in,
                              void* d_out, int out_size, void* d_ws, size_t ws_size,
                              hipStream_t stream)
{
    const float* x      = (const float*)d_in[0];
    const int*   y      = (const int*)  d_in[1];
    const float* muQ    = (const float*)d_in[3];
    const float* sigQ   = (const float*)d_in[4];
    const float* mu_w   = (const float*)d_in[5];
    const float* mu_b   = (const float*)d_in[6];
    const float* sig_w  = (const float*)d_in[7];
    const float* sig_b  = (const float*)d_in[8];
    const float* skel_w = (const float*)d_in[9];
    const float* skel_b = (const float*)d_in[10];
    const float* Wq     = (const float*)d_in[11];
    const float* bq     = (const float*)d_in[12];
    const float* Wk     = (const float*)d_in[13];
    const float* bk     = (const float*)d_in[14];
    const float* Wv     = (const float*)d_in[15];
    const float* bv     = (const float*)d_in[16];
    const float* Wo     = (const float*)d_in[17];
    const float* bo     = (const float*)d_in[18];
    const float* g1     = (const float*)d_in[19];
    const float* c1     = (const float*)d_in[20];
    const float* g2     = (const float*)d_in[21];
    const float* c2     = (const float*)d_in[22];
    const float* W1     = (const float*)d_in[23];
    const float* b1     = (const float*)d_in[24];
    const float* W2     = (const float*)d_in[25];
    const float* b2     = (const float*)d_in[26];

    // ws: z (33.6) + qT (33.8) + k,v (67.2) + 24 split weights (25.2) + cent/P/assign (~3) ≈ 163MB
    float*  z    = (float*)d_ws;
    float*  qb   = z  + NBUF;          // transposed q [128][64][1032]
    float*  kb   = qb + QTSZ;
    float*  vb   = kb + NBUF;
    ushort* wThi = (ushort*)(vb + NBUF);       // [8][3][512][512] f16 hi
    ushort* wTlo = wThi + 24*DD;               // f16 lo
    float*  centbuf  = (float*)(wTlo + 24*DD); // [128][10][64]
    float*  P        = centbuf + (size_t)NBH*NC*DH;          // [128][10][512]
    unsigned char* assignbuf = (unsigned char*)(P + (size_t)NBH*NC*D);  // [128][1032]

    convert_w<<<dim3(8, 8, 24), 256, 0, stream>>>(Wq, Wk, Wv, wThi, wTlo);

    embed_kernel<<<dim3(258, BATCH), 256, 0, stream>>>(
        x, y, muQ, sigQ, mu_w, mu_b, sig_w, sig_b, skel_w, skel_b, z);

    for (int l = 0; l < NLAYERS; ++l) {
        gemm_qkv<<<dim3(4, 129, 3), 256, 0, stream>>>(
            z, wThi + (size_t)l*3*DD, wTlo + (size_t)l*3*DD,
            bq + l*D, bk + l*D, bv + l*D, qb, kb, vb, MR);
        attn_kernel<<<NBH, 1024, 0, stream>>>(qb, kb, vb, centbuf, assignbuf);
        pproj_kernel<<<dim3(NBH, 2), 256, 0, stream>>>(centbuf, Wo + (size_t)l*DD, P);
        ffn_ln_kernel<<<MR, 256, 0, stream>>>(z, P, assignbuf, bo + l*D,
            g1 + (size_t)l*D, c1 + (size_t)l*D,
            W1 + (size_t)l*D*DFF, b1 + (size_t)l*DFF,
            W2 + (size_t)l*DFF*D, b2 + (size_t)l*D,
            g2 + (size_t)l*D, c2 + (size_t)l*D);
    }
    extract_kernel<<<64, 256, 0, stream>>>(z, (float*)d_out);

    (void)in_sizes; (void)n_in; (void)out_size; (void)ws_size;
}

// Round 13
// 4382.719 us; speedup vs baseline: 1.1998x; 1.1992x over previous
//
#include <hip/hip_runtime.h>
#include <hip/hip_fp16.h>
#include <math.h>

#define D 512
#define H 8
#define DH 64
#define NLAYERS 8
#define DFF 8
#define NC 10
#define KITERS 10
#define SEQ 1026
#define SEQP 1032
#define BATCH 16
#define MR (BATCH*SEQ)            // 16416 rows
#define NBUF ((size_t)MR * D)     // floats per big activation buffer
#define DD ((size_t)D * D)
#define NBH (BATCH*H)             // 128
#define KSPLIT 64
#define KCH 48                    // 64*48 = 3072 = D*MAXA

typedef _Float16 f16;
typedef f16 f16x8 __attribute__((ext_vector_type(8)));
typedef float f32x4 __attribute__((ext_vector_type(4)));

__device__ __forceinline__ void split2(float x, float y, unsigned& uh, unsigned& ul) {
    __half hx = __float2half_rn(x), hy = __float2half_rn(y);
    __half lx = __float2half_rn(x - __half2float(hx));
    __half ly = __float2half_rn(y - __half2float(hy));
    uh = (unsigned)__half_as_ushort(hx) | ((unsigned)__half_as_ushort(hy) << 16);
    ul = (unsigned)__half_as_ushort(lx) | ((unsigned)__half_as_ushort(ly) << 16);
}

__device__ __forceinline__ float pe_val(int s, int d) {
    float e = (float)(d & ~1);
    float dv = expf(e * (-9.210340371976184f / 512.0f));   // ln(10000)/512
    float ph = (float)s * dv;
    return (d & 1) ? cosf(ph) : sinf(ph);
}

// ---------------- weight split+transpose (Wq,Wk,Wv): W[k][n] -> [l][3][n][k] f16 hi/lo ----------------
__launch_bounds__(256)
__global__ void convert_w(const float* __restrict__ Wq, const float* __restrict__ Wk,
                          const float* __restrict__ Wv,
                          ushort* __restrict__ whiT, ushort* __restrict__ wloT)
{
    __shared__ float tile[64][65];
    const int tid = threadIdx.x;
    const int k0 = blockIdx.x * 64, n0 = blockIdx.y * 64, m = blockIdx.z;
    const int which = m % 3, lyr = m / 3;
    const float* base;
    switch (which) { case 0: base = Wq; break; case 1: base = Wk; break;
                     default: base = Wv; }
    const float* W = base + (size_t)lyr * DD;
    {
        int r = tid >> 4, c = (tid & 15) * 4;
        #pragma unroll
        for (int p = 0; p < 4; ++p) {
            float4 v = *(const float4*)&W[(size_t)(k0 + r + p*16)*D + n0 + c];
            tile[r + p*16][c]   = v.x; tile[r + p*16][c+1] = v.y;
            tile[r + p*16][c+2] = v.z; tile[r + p*16][c+3] = v.w;
        }
    }
    __syncthreads();
    ushort* ohp = whiT + (size_t)m * DD;
    ushort* olp = wloT + (size_t)m * DD;
    {
        int nl = tid >> 3, kc = (tid & 7) * 8;
        #pragma unroll
        for (int p = 0; p < 2; ++p) {
            int n = nl + p*32;
            uint4 UH, UL;
            split2(tile[kc+0][n], tile[kc+1][n], UH.x, UL.x);
            split2(tile[kc+2][n], tile[kc+3][n], UH.y, UL.y);
            split2(tile[kc+4][n], tile[kc+5][n], UH.z, UL.z);
            split2(tile[kc+6][n], tile[kc+7][n], UH.w, UL.w);
            size_t off = (size_t)(n0 + n)*D + k0 + kc;
            *(uint4*)&ohp[off] = UH;
            *(uint4*)&olp[off] = UL;
        }
    }
}

// ---------------- mu/sig K-split partial GEMV: grid (KSPLIT, 2) ----------------
// pbuf[p][kc][b][n] = sum_{k in chunk} x[b][k] * W[k][n]
__launch_bounds__(256)
__global__ void embed_ms_part(const int* __restrict__ y,
    const float* __restrict__ muQ, const float* __restrict__ sigQ,
    const float* __restrict__ mu_w, const float* __restrict__ sig_w,
    float* __restrict__ pbuf)
{
    __shared__ float xs[BATCH][KCH];
    const int tid = threadIdx.x;
    const int kc = blockIdx.x, p = blockIdx.y;
    const float* Q = p ? sigQ : muQ;
    const float* W = p ? sig_w : mu_w;
    for (int i = tid; i < BATCH*KCH; i += 256) {
        int b = i / KCH, k = i - b*KCH;
        int gk = kc*KCH + k;
        int a = y[b*6 + (gk >> 9)];
        xs[b][k] = Q[a*D + (gk & 511)];
    }
    __syncthreads();
    const int n0 = tid*2;
    float a0[BATCH], a1[BATCH];
    #pragma unroll
    for (int b = 0; b < BATCH; ++b) { a0[b] = 0.f; a1[b] = 0.f; }
    #pragma unroll 4
    for (int k = 0; k < KCH; ++k) {
        const float2 wv = *(const float2*)&W[(size_t)(kc*KCH + k)*D + n0];
        #pragma unroll
        for (int b = 0; b < BATCH; ++b) {
            float xv = xs[b][k];
            a0[b] += xv * wv.x;
            a1[b] += xv * wv.y;
        }
    }
    float* pp = pbuf + ((size_t)(p*KSPLIT + kc)*BATCH)*D;
    #pragma unroll
    for (int b = 0; b < BATCH; ++b)
        *(float2*)&pp[(size_t)b*D + n0] = make_float2(a0[b], a1[b]);
}

// ---------------- mu/sig reduce + bias + PE -> z rows 0/1: grid (2, BATCH) ----------------
__launch_bounds__(256)
__global__ void embed_ms_reduce(const float* __restrict__ pbuf,
    const float* __restrict__ mu_b, const float* __restrict__ sig_b,
    float* __restrict__ z)
{
    const int tid = threadIdx.x;
    const int p = blockIdx.x, b = blockIdx.y;
    const float* bb = p ? sig_b : mu_b;
    #pragma unroll
    for (int half = 0; half < 2; ++half) {
        const int d = tid + half*256;
        float s = bb[d];
        const float* pp = pbuf + ((size_t)(p*KSPLIT)*BATCH + b)*D + d;
        #pragma unroll 8
        for (int kc = 0; kc < KSPLIT; ++kc)
            s += pp[(size_t)kc*BATCH*D];
        z[((size_t)b*SEQ + p)*D + d] = s + pe_val(p, d);
    }
}

// ---------------- embed skel path: grid (256, BATCH) ----------------
__launch_bounds__(256)
__global__ void embed_kernel(const float* __restrict__ x,
    const float* __restrict__ skel_w, const float* __restrict__ skel_b,
    float* __restrict__ z)
{
    __shared__ float xin[600];
    const int bx = blockIdx.x, b = blockIdx.y, tid = threadIdx.x;
    const int f0 = bx * 4;
    for (int idx = tid; idx < 600; idx += 256) {
        int i = idx >> 2, ff = idx & 3;
        xin[idx] = x[((size_t)(b*150 + i))*1024 + f0 + ff];
    }
    __syncthreads();
    const float4* x4 = (const float4*)xin;
    for (int dd = 0; dd < 2; ++dd) {
        const int d = tid + dd*256;
        float a0, a1, a2, a3;
        a0 = a1 = a2 = a3 = skel_b[d];
        for (int i = 0; i < 150; ++i) {
            float4 xv = x4[i];
            float w = skel_w[(size_t)i*D + d];
            a0 += xv.x*w; a1 += xv.y*w; a2 += xv.z*w; a3 += xv.w*w;
        }
        float a[4] = {a0, a1, a2, a3};
        #pragma unroll
        for (int ff = 0; ff < 4; ++ff) {
            int s = f0 + ff + 2;
            z[((size_t)b*SEQ + s)*D + d] = a[ff] + pe_val(s, d);
        }
    }
}

// ---------------- fused QKV split-f16 MFMA GEMM ----------------
__launch_bounds__(256)
__global__ void gemm_qkv(const float* __restrict__ A,
                         const ushort* __restrict__ Bhi_b, const ushort* __restrict__ Blo_b,
                         const float* __restrict__ bq, const float* __restrict__ bk,
                         const float* __restrict__ bv,
                         float* __restrict__ outbase, int M)
{
    __shared__ ushort Ah[128*40], Al[128*40], Bh[128*40], Bl[128*40];
    const int tid = threadIdx.x;
    const int m0 = blockIdx.y * 128, n0 = blockIdx.x * 128;
    const int zz = blockIdx.z;
    const ushort* Bhi = Bhi_b + (size_t)zz * DD;
    const ushort* Blo = Blo_b + (size_t)zz * DD;
    const float* bias = (zz == 0) ? bq : (zz == 1) ? bk : bv;
    float* out = outbase + (size_t)zz * NBUF;
    const int l = tid & 63, wv = tid >> 6;
    const int wr = wv >> 1, wc = wv & 1;

    f32x4 acc[4][4];
    #pragma unroll
    for (int mi = 0; mi < 4; ++mi)
        #pragma unroll
        for (int ni = 0; ni < 4; ++ni) acc[mi][ni] = (f32x4){0.f, 0.f, 0.f, 0.f};

    const int ar_s = tid >> 1, ac_s = (tid & 1) * 16;
    const bool va = (m0 + ar_s) < M;
    const int r0 = (tid*2) >> 2,   kc0 = ((tid*2) & 3) * 8;
    const int r1 = (tid*2+1) >> 2, kc1 = ((tid*2+1) & 3) * 8;
    const float4 fz = make_float4(0.f, 0.f, 0.f, 0.f);

    for (int kt = 0; kt < 16; ++kt) {
        const int kb = kt * 32;
        float4 a0 = fz, a1 = fz, a2 = fz, a3 = fz;
        if (va) {
            const float4* ap = (const float4*)&A[(size_t)(m0 + ar_s)*D + kb + ac_s];
            a0 = ap[0]; a1 = ap[1]; a2 = ap[2]; a3 = ap[3];
        }
        uint4 bh0 = *(const uint4*)&Bhi[(size_t)(n0+r0)*D + kb + kc0];
        uint4 bh1 = *(const uint4*)&Bhi[(size_t)(n0+r1)*D + kb + kc1];
        uint4 bl0 = *(const uint4*)&Blo[(size_t)(n0+r0)*D + kb + kc0];
        uint4 bl1 = *(const uint4*)&Blo[(size_t)(n0+r1)*D + kb + kc1];

        uint4 AH0, AL0, AH1, AL1;
        split2(a0.x, a0.y, AH0.x, AL0.x); split2(a0.z, a0.w, AH0.y, AL0.y);
        split2(a1.x, a1.y, AH0.z, AL0.z); split2(a1.z, a1.w, AH0.w, AL0.w);
        split2(a2.x, a2.y, AH1.x, AL1.x); split2(a2.z, a2.w, AH1.y, AL1.y);
        split2(a3.x, a3.y, AH1.z, AL1.z); split2(a3.z, a3.w, AH1.w, AL1.w);

        if (kt) __syncthreads();
        *(uint4*)&Ah[ar_s*40 + ac_s]     = AH0;
        *(uint4*)&Ah[ar_s*40 + ac_s + 8] = AH1;
        *(uint4*)&Al[ar_s*40 + ac_s]     = AL0;
        *(uint4*)&Al[ar_s*40 + ac_s + 8] = AL1;
        *(uint4*)&Bh[r0*40 + kc0] = bh0;  *(uint4*)&Bh[r1*40 + kc1] = bh1;
        *(uint4*)&Bl[r0*40 + kc0] = bl0;  *(uint4*)&Bl[r1*40 + kc1] = bl1;
        __syncthreads();

        const int ko = (l >> 4) * 8;
        f16x8 bhf[4], blf[4];
        #pragma unroll
        for (int ni = 0; ni < 4; ++ni) {
            int br = wc*64 + ni*16 + (l & 15);
            bhf[ni] = *(const f16x8*)&Bh[br*40 + ko];
            blf[ni] = *(const f16x8*)&Bl[br*40 + ko];
        }
        #pragma unroll
        for (int mi = 0; mi < 4; ++mi) {
            int ar = wr*64 + mi*16 + (l & 15);
            f16x8 ahf = *(const f16x8*)&Ah[ar*40 + ko];
            f16x8 alf = *(const f16x8*)&Al[ar*40 + ko];
            #pragma unroll
            for (int ni = 0; ni < 4; ++ni) {
                acc[mi][ni] = __builtin_amdgcn_mfma_f32_16x16x32_f16(ahf, bhf[ni], acc[mi][ni], 0, 0, 0);
                acc[mi][ni] = __builtin_amdgcn_mfma_f32_16x16x32_f16(ahf, blf[ni], acc[mi][ni], 0, 0, 0);
                acc[mi][ni] = __builtin_amdgcn_mfma_f32_16x16x32_f16(alf, bhf[ni], acc[mi][ni], 0, 0, 0);
            }
        }
    }

    const int col_base = n0 + wc*64 + (l & 15);
    const int row_base = m0 + wr*64 + ((l >> 4) << 2);
    #pragma unroll
    for (int ni = 0; ni < 4; ++ni) {
        const int col = col_base + ni*16;
        const float bv2 = bias[col];
        #pragma unroll
        for (int mi = 0; mi < 4; ++mi) {
            #pragma unroll
            for (int e = 0; e < 4; ++e) {
                const int row = row_base + mi*16 + e;
                if (row >= M) continue;
                float val = acc[mi][ni][e] + bv2;
                int bb = row / SEQ;
                int ss = row - bb*SEQ;
                int hh = col >> 6, dh = col & 63;
                out[((size_t)(bb*H + hh)*SEQ + ss)*DH + dh] = val;
            }
        }
    }
}

// ---------------- clustered attention (round-7 internals): 1 block (1024 thr) per (b,h) ----------------
__launch_bounds__(1024, 4)
__global__ void attn_kernel(const float* __restrict__ q, const float* __restrict__ kk,
                            const float* __restrict__ v,
                            float* __restrict__ centout, unsigned char* __restrict__ assignout)
{
    __shared__ float At[NC][SEQP];       // 41.3 KB; doubles as part[16][NC][DH]
    __shared__ float cent[NC][DH];
    __shared__ float tailrow[2][DH];
    __shared__ float cnorm[NC];
    __shared__ int   cnt[NC];
    __shared__ int   chg;
    __shared__ unsigned char assign[1028];
    __shared__ float redA[16][NC];
    __shared__ float redB[16][NC];
    __shared__ float Mc[NC];
    __shared__ float Sinv[NC];

    const int tid = threadIdx.x;
    const int wv = tid >> 6, lane = tid & 63;
    const int bh = blockIdx.x;
    const float* qh = q  + (size_t)bh * SEQ * DH;
    const float* kh = kk + (size_t)bh * SEQ * DH;
    const float* vh = v  + (size_t)bh * SEQ * DH;
    float* part = &At[0][0];

    if (tid < NC*DH) ((float*)cent)[tid] = qh[tid];
    if (tid >= NC*DH && tid < NC*DH + 2*DH) ((float*)tailrow)[tid - NC*DH] = qh[1024*DH + (tid - NC*DH)];
    __syncthreads();

    const float4* qrow4 = (const float4*)(qh + (size_t)tid * DH);
    int prev_a = -1, prev_t = -1;

    for (int iter = 0; iter <= KITERS; ++iter) {
        if (tid < NC) {
            float sn = 0.f;
            #pragma unroll
            for (int i = 0; i < 16; ++i) {
                float4 cv = *(const float4*)&cent[tid][i*4];
                sn += cv.x*cv.x + cv.y*cv.y + cv.z*cv.z + cv.w*cv.w;
            }
            cnorm[tid] = sn;
            cnt[tid] = 0;
        }
        if (tid == 0) chg = 0;
        __syncthreads();

        int a_reg;
        {
            float acc[NC];
            #pragma unroll
            for (int c = 0; c < NC; ++c) acc[c] = 0.f;
            #pragma unroll 8
            for (int kq = 0; kq < 16; ++kq) {
                float4 qv = qrow4[kq];
                #pragma unroll
                for (int c = 0; c < NC; ++c) {
                    float4 cv = *(const float4*)&cent[c][kq*4];
                    acc[c] += qv.x*cv.x + qv.y*cv.y + qv.z*cv.z + qv.w*cv.w;
                }
            }
            int best = 0; float bd = 1e30f;
            #pragma unroll
            for (int c = 0; c < NC; ++c) {
                float dd = cnorm[c] - 2.f*acc[c];
                if (dd < bd) { bd = dd; best = c; }
            }
            a_reg = best;
            assign[tid] = (unsigned char)best;
        }
        {
            unsigned long long mm = __ballot(a_reg != prev_a);
            if (lane == 0 && mm) atomicAdd(&chg, 1);
            prev_a = a_reg;
        }
        if (iter < KITERS) {
            #pragma unroll
            for (int c = 0; c < NC; ++c) {
                unsigned long long m = __ballot(a_reg == c);
                if (lane == 0 && m) atomicAdd(&cnt[c], __popcll(m));
            }
        }
        if (tid < 2) {
            int best = 0; float bd = 1e30f;
            #pragma unroll
            for (int c = 0; c < NC; ++c) {
                float acc = 0.f;
                #pragma unroll
                for (int i = 0; i < 64; ++i) acc += tailrow[tid][i]*cent[c][i];
                float dd = cnorm[c] - 2.f*acc;
                if (dd < bd) { bd = dd; best = c; }
            }
            assign[1024 + tid] = (unsigned char)best;
            if (best != prev_t) atomicAdd(&chg, 1);
            prev_t = best;
            if (iter < KITERS) atomicAdd(&cnt[best], 1);
        }
        __syncthreads();
        if (iter == KITERS) break;
        if (chg == 0) break;    // bitwise-exact fixed point

        {
            float accq[NC];
            #pragma unroll
            for (int c = 0; c < NC; ++c) accq[c] = 0.f;
            const int s0 = wv * 64;
            #pragma unroll 8
            for (int i = 0; i < 64; ++i) {
                int s = s0 + i;
                float qv = qh[(size_t)s*DH + lane];
                int c = assign[s];
                #pragma unroll
                for (int cc = 0; cc < NC; ++cc) accq[cc] += (cc == c) ? qv : 0.f;
            }
            if (wv < 2) {
                int c = assign[1024 + wv];
                float qv = tailrow[wv][lane];
                #pragma unroll
                for (int cc = 0; cc < NC; ++cc) accq[cc] += (cc == c) ? qv : 0.f;
            }
            #pragma unroll
            for (int c = 0; c < NC; ++c) part[(wv*NC + c)*DH + lane] = accq[c];
        }
        __syncthreads();
        if (tid < NC*DH) {
            int c = tid >> 6;
            float s = 0.f;
            #pragma unroll
            for (int w = 0; w < 16; ++w) s += part[w*(NC*DH) + tid];
            ((float*)cent)[tid] = s / fmaxf((float)cnt[c], 1.f);
        }
        __syncthreads();
    }

    // ---- logits ----
    if (tid < 2*DH) ((float*)tailrow)[tid] = kh[1024*DH + tid];
    __syncthreads();

    float lg[NC], lgt[NC];
    {
        const float4* krow4 = (const float4*)(kh + (size_t)tid * DH);
        #pragma unroll
        for (int c = 0; c < NC; ++c) lg[c] = 0.f;
        #pragma unroll 8
        for (int kq = 0; kq < 16; ++kq) {
            float4 kv = krow4[kq];
            #pragma unroll
            for (int c = 0; c < NC; ++c) {
                float4 cv = *(const float4*)&cent[c][kq*4];
                lg[c] += kv.x*cv.x + kv.y*cv.y + kv.z*cv.z + kv.w*cv.w;
            }
        }
        #pragma unroll
        for (int c = 0; c < NC; ++c) lg[c] *= 0.125f;
    }
    if (tid < 2) {
        #pragma unroll
        for (int c = 0; c < NC; ++c) {
            float acc = 0.f;
            #pragma unroll
            for (int i = 0; i < 64; ++i) acc += tailrow[tid][i]*cent[c][i];
            lgt[c] = 0.125f * acc;
        }
    }

    #pragma unroll
    for (int c = 0; c < NC; ++c) {
        float m = lg[c];
        if (tid < 2) m = fmaxf(m, lgt[c]);
        #pragma unroll
        for (int off = 32; off; off >>= 1) m = fmaxf(m, __shfl_xor(m, off, 64));
        if (lane == 0) redA[wv][c] = m;
    }
    __syncthreads();
    if (tid < NC) {
        float m = redA[0][tid];
        #pragma unroll
        for (int w = 1; w < 16; ++w) m = fmaxf(m, redA[w][tid]);
        Mc[tid] = m;
    }
    __syncthreads();
    #pragma unroll
    for (int c = 0; c < NC; ++c) lg[c] = expf(lg[c] - Mc[c]);
    if (tid < 2) {
        #pragma unroll
        for (int c = 0; c < NC; ++c) lgt[c] = expf(lgt[c] - Mc[c]);
    }
    #pragma unroll
    for (int c = 0; c < NC; ++c) {
        float s = lg[c] + ((tid < 2) ? lgt[c] : 0.f);
        #pragma unroll
        for (int off = 32; off; off >>= 1) s += __shfl_xor(s, off, 64);
        if (lane == 0) redB[wv][c] = s;
    }
    __syncthreads();
    if (tid < NC) {
        float s = 0.f;
        #pragma unroll
        for (int w = 0; w < 16; ++w) s += redB[w][tid];
        Sinv[tid] = 1.f / s;
    }
    __syncthreads();
    #pragma unroll
    for (int c = 0; c < NC; ++c) At[c][tid] = lg[c] * Sinv[c];
    if (tid < 2) {
        #pragma unroll
        for (int c = 0; c < NC; ++c) At[c][1024 + tid] = lgt[c] * Sinv[c];
    }
    __syncthreads();

    // ---- A @ v -> cent_out; export cent_out + assign ----
    {
        float accv[NC];
        #pragma unroll
        for (int c = 0; c < NC; ++c) accv[c] = 0.f;
        const int s0 = wv * 64;
        for (int i = 0; i < 64; i += 4) {
            float vv0 = vh[(size_t)(s0+i  )*DH + lane];
            float vv1 = vh[(size_t)(s0+i+1)*DH + lane];
            float vv2 = vh[(size_t)(s0+i+2)*DH + lane];
            float vv3 = vh[(size_t)(s0+i+3)*DH + lane];
            #pragma unroll
            for (int c = 0; c < NC; ++c) {
                float4 av = *(const float4*)&At[c][s0+i];
                accv[c] += av.x*vv0 + av.y*vv1 + av.z*vv2 + av.w*vv3;
            }
        }
        if (wv < 2) {
            int s = 1024 + wv;
            float vv = vh[(size_t)s*DH + lane];
            #pragma unroll
            for (int c = 0; c < NC; ++c) accv[c] += At[c][s] * vv;
        }
        __syncthreads();
        #pragma unroll
        for (int c = 0; c < NC; ++c) part[(wv*NC + c)*DH + lane] = accv[c];
    }
    __syncthreads();
    if (tid < NC*DH) {
        float s = 0.f;
        #pragma unroll
        for (int w = 0; w < 16; ++w) s += part[w*(NC*DH) + tid];
        centout[(size_t)bh*(NC*DH) + tid] = s;
    }
    for (int i = tid; i < SEQ; i += 1024)
        assignout[(size_t)bh*SEQP + i] = assign[i];
}

// ---------------- P projection: P[bh][c][n] = cent_out[bh][c] @ Wo_h (fp32 exact) ----------------
__launch_bounds__(256)
__global__ void pproj_kernel(const float* __restrict__ centout, const float* __restrict__ Wo,
                             float* __restrict__ P)
{
    __shared__ float cs[NC][DH];
    const int tid = threadIdx.x;
    const int bh = blockIdx.x, h = bh & 7;
    const int n = blockIdx.y * 256 + tid;
    for (int i = tid; i < NC*DH; i += 256) ((float*)cs)[i] = centout[(size_t)bh*(NC*DH) + i];
    __syncthreads();
    float acc[NC];
    #pragma unroll
    for (int c = 0; c < NC; ++c) acc[c] = 0.f;
    #pragma unroll 8
    for (int d = 0; d < DH; ++d) {
        float wv = Wo[(size_t)(h*DH + d)*D + n];
        #pragma unroll
        for (int c = 0; c < NC; ++c) acc[c] += cs[c][d] * wv;
    }
    #pragma unroll
    for (int c = 0; c < NC; ++c)
        P[((size_t)bh*NC + c)*D + n] = acc[c];
}

// ---------------- fused o-gather + residual + LN1 + FFN + residual + LN2 ----------------
__launch_bounds__(256)
__global__ void ffn_ln_kernel(float* __restrict__ z,
    const float* __restrict__ P, const unsigned char* __restrict__ assignbuf,
    const float* __restrict__ bo,
    const float* __restrict__ g1, const float* __restrict__ c1,
    const float* __restrict__ W1, const float* __restrict__ b1,
    const float* __restrict__ W2, const float* __restrict__ b2,
    const float* __restrict__ g2, const float* __restrict__ c2)
{
    __shared__ float red[8];
    __shared__ float redh[4][DFF];
    const int row = blockIdx.x, tid = threadIdx.x;
    const int lane = tid & 63, wid = tid >> 6;
    const int b = row / SEQ, s = row - b*SEQ;

    float x0 = z[(size_t)row*D + tid]       + bo[tid];
    float x1 = z[(size_t)row*D + tid + 256] + bo[tid + 256];
    #pragma unroll
    for (int h = 0; h < H; ++h) {
        int a = assignbuf[(size_t)(b*H + h)*SEQP + s];
        const float* Pr = P + ((size_t)(b*H + h)*NC + a)*D;
        x0 += Pr[tid];
        x1 += Pr[tid + 256];
    }

    float sm = x0 + x1, ss = x0*x0 + x1*x1;
    #pragma unroll
    for (int off = 32; off; off >>= 1) {
        sm += __shfl_xor(sm, off, 64);
        ss += __shfl_xor(ss, off, 64);
    }
    if (lane == 0) { red[wid] = sm; red[4 + wid] = ss; }
    __syncthreads();
    float tot  = red[0] + red[1] + red[2] + red[3];
    float tot2 = red[4] + red[5] + red[6] + red[7];
    float mean = tot * (1.f/512.f);
    float var  = tot2 * (1.f/512.f) - mean*mean;
    float rstd = rsqrtf(var + 1e-5f);
    float za = (x0 - mean)*rstd*g1[tid]       + c1[tid];
    float zb = (x1 - mean)*rstd*g1[tid + 256] + c1[tid + 256];

    float p[DFF];
    #pragma unroll
    for (int j = 0; j < DFF; ++j)
        p[j] = za * W1[(size_t)tid*DFF + j] + zb * W1[(size_t)(tid+256)*DFF + j];
    #pragma unroll
    for (int off = 32; off; off >>= 1)
        #pragma unroll
        for (int j = 0; j < DFF; ++j) p[j] += __shfl_xor(p[j], off, 64);
    if (lane == 0) {
        #pragma unroll
        for (int j = 0; j < DFF; ++j) redh[wid][j] = p[j];
    }
    __syncthreads();
    float hv[DFF];
    #pragma unroll
    for (int j = 0; j < DFF; ++j)
        hv[j] = fmaxf(redh[0][j] + redh[1][j] + redh[2][j] + redh[3][j] + b1[j], 0.f);
    float y0 = b2[tid], y1 = b2[tid + 256];
    #pragma unroll
    for (int j = 0; j < DFF; ++j) {
        y0 += hv[j] * W2[(size_t)j*D + tid];
        y1 += hv[j] * W2[(size_t)j*D + tid + 256];
    }
    float t0 = za + y0, t1 = zb + y1;
    float s2 = t0 + t1, ss2 = t0*t0 + t1*t1;
    #pragma unroll
    for (int off = 32; off; off >>= 1) {
        s2  += __shfl_xor(s2,  off, 64);
        ss2 += __shfl_xor(ss2, off, 64);
    }
    if (lane == 0) { red[wid] = s2; red[4 + wid] = ss2; }
    __syncthreads();
    float tt  = red[0] + red[1] + red[2] + red[3];
    float tt2 = red[4] + red[5] + red[6] + red[7];
    float m2 = tt * (1.f/512.f);
    float v2 = tt2 * (1.f/512.f) - m2*m2;
    float rstd2 = rsqrtf(v2 + 1e-5f);
    float* zo = z + (size_t)row * D;
    zo[tid]       = (t0 - m2)*rstd2*g2[tid]       + c2[tid];
    zo[tid + 256] = (t1 - m2)*rstd2*g2[tid + 256] + c2[tid + 256];
}

// ---------------- extract mu / logvar ----------------
__launch_bounds__(256)
__global__ void extract_kernel(const float* __restrict__ z, float* __restrict__ out) {
    int i = blockIdx.x * 256 + threadIdx.x;
    if (i >= 2*BATCH*D) return;
    int half = i >> 13;
    int j = i & 8191;
    int b = j >> 9, d = j & 511;
    out[i] = z[((size_t)b*SEQ + half)*D + d];
}

extern "C" void kernel_launch(void* const* d_in, const int* in_sizes, int n_in,
                              void* d_out, int out_size, void* d_ws, size_t ws_size,
                              hipStream_t stream)
{
    const float* x      = (const float*)d_in[0];
    const int*   y      = (const int*)  d_in[1];
    const float* muQ    = (const float*)d_in[3];
    const float* sigQ   = (const float*)d_in[4];
    const float* mu_w   = (const float*)d_in[5];
    const float* mu_b   = (const float*)d_in[6];
    const float* sig_w  = (const float*)d_in[7];
    const float* sig_b  = (const float*)d_in[8];
    const float* skel_w = (const float*)d_in[9];
    const float* skel_b = (const float*)d_in[10];
    const float* Wq     = (const float*)d_in[11];
    const float* bq     = (const float*)d_in[12];
    const float* Wk     = (const float*)d_in[13];
    const float* bk     = (const float*)d_in[14];
    const float* Wv     = (const float*)d_in[15];
    const float* bv     = (const float*)d_in[16];
    const float* Wo     = (const float*)d_in[17];
    const float* bo     = (const float*)d_in[18];
    const float* g1     = (const float*)d_in[19];
    const float* c1     = (const float*)d_in[20];
    const float* g2     = (const float*)d_in[21];
    const float* c2     = (const float*)d_in[22];
    const float* W1     = (const float*)d_in[23];
    const float* b1     = (const float*)d_in[24];
    const float* W2     = (const float*)d_in[25];
    const float* b2     = (const float*)d_in[26];

    float*  z    = (float*)d_ws;
    float*  qb   = z  + NBUF;     // q,k,v contiguous
    float*  kb   = qb + NBUF;
    float*  vb   = kb + NBUF;
    ushort* wThi = (ushort*)(vb + NBUF);       // [8][3][512][512] f16 hi
    ushort* wTlo = wThi + 24*DD;               // f16 lo
    float*  centbuf  = (float*)(wTlo + 24*DD); // [128][10][64]
    float*  P        = centbuf + (size_t)NBH*NC*DH;          // [128][10][512]
    unsigned char* assignbuf = (unsigned char*)(P + (size_t)NBH*NC*D);  // [128][1032]
    float*  pbuf = (float*)(assignbuf + (size_t)NBH*SEQP);   // [2][64][16][512] = 4.2MB

    convert_w<<<dim3(8, 8, 24), 256, 0, stream>>>(Wq, Wk, Wv, wThi, wTlo);

    embed_ms_part<<<dim3(KSPLIT, 2), 256, 0, stream>>>(y, muQ, sigQ, mu_w, sig_w, pbuf);
    embed_ms_reduce<<<dim3(2, BATCH), 256, 0, stream>>>(pbuf, mu_b, sig_b, z);
    embed_kernel<<<dim3(256, BATCH), 256, 0, stream>>>(x, skel_w, skel_b, z);

    for (int l = 0; l < NLAYERS; ++l) {
        gemm_qkv<<<dim3(4, 129, 3), 256, 0, stream>>>(
            z, wThi + (size_t)l*3*DD, wTlo + (size_t)l*3*DD,
            bq + l*D, bk + l*D, bv + l*D, qb, MR);
        attn_kernel<<<NBH, 1024, 0, stream>>>(qb, kb, vb, centbuf, assignbuf);
        pproj_kernel<<<dim3(NBH, 2), 256, 0, stream>>>(centbuf, Wo + (size_t)l*DD, P);
        ffn_ln_kernel<<<MR, 256, 0, stream>>>(z, P, assignbuf, bo + l*D,
            g1 + (size_t)l*D, c1 + (size_t)l*D,
            W1 + (size_t)l*D*DFF, b1 + (size_t)l*DFF,
            W2 + (size_t)l*DFF*D, b2 + (size_t)l*D,
            g2 + (size_t)l*D, c2 + (size_t)l*D);
    }
    extract_kernel<<<64, 256, 0, stream>>>(z, (float*)d_out);

    (void)in_sizes; (void)n_in; (void)out_size; (void)ws_size;
}